// Round 10
// baseline (165.450 us; speedup 1.0000x reference)
//
#include <hip/hip_runtime.h>

// Problem constants: B=4, De=Do=64, T=4, H=W=128, PATCH=7, R=3
#define ATTN_OFF 4194304                 // B*Do*H*W (mem region size in floats)
// packed attn ws: [b][G=256][t][13][64] float4  = 3,407,872 float4s
#define WS_F4_COUNT 3407872ull

// ---------------------------------------------------------------------------
// K1 v9: correlation logits, k3-v5 phase structure (8 chunks x 8 channels).
//  - R9 showed k1 v8 (16 x 4-ch phases) at 75 us vs k3 v5 (4 x 8-ch phases)
//    at ~45 us with IDENTICAL total LDS work per CU: the difference is
//    barrier/latency-exposure events. This clones k3's per-phase shape:
//    1064 staged items, 2-quad LDS (18,816 B -> 4 blocks/CU in ~80KB pool).
//  - tile 32x8, 1 px/thread, grid (4,16,16) = 1024 blocks.
//  - conflict-free staging: 4-channel gather -> one ds_write_b128.
//  - channel order ascending per d (q0..q7 over quad0,quad1) -> numerics
//    identical to v8.
// ---------------------------------------------------------------------------
__global__ __launch_bounds__(256) void k1_corr(
    const float* __restrict__ m_in, const float* __restrict__ q_in,
    float* __restrict__ out)
{
  const int b = blockIdx.z >> 2, t = blockIdx.z & 3;
  const int h0 = blockIdx.y * 8, w0 = blockIdx.x * 32;
  const int tid = threadIdx.x;
  const int tx = tid & 31, ty = tid >> 5;
  const int h = h0 + ty, w = w0 + tx;

  // [quad][y 0..13][x 0..41][c%4]; slot xi+1 <-> gx = w0-3+xi
  __shared__ float m_s[2][14][42][4];   // 18,816 B

  float acc[49];
#pragma unroll
  for (int d = 0; d < 49; ++d) acc[d] = 0.f;

#pragma unroll 1
  for (int cc = 0; cc < 8; ++cc) {      // 8 chunks x 8 channels (2 quads)
    __syncthreads();                    // prev chunk's reads complete
    {
      // 1064 items = 2 quads x 14 rows x 38 xi ; gather -> one b128 write
      const float* base = m_in + (((b * 64 + cc * 8) * 4 + t) << 14);
#pragma unroll
      for (int k = 0; k < 5; ++k) {
        const int item = tid + (k << 8);
        if (item < 1064) {
          const int quad = item >= 532;
          const int rem  = item - 532 * quad;
          const int y  = rem / 38;             // magic-mul
          const int xi = rem - 38 * y;
          const int gy = h0 - 3 + y, gx = w0 - 3 + xi;
          float4 v = make_float4(0.f, 0.f, 0.f, 0.f);
          if ((unsigned)gy < 128u && (unsigned)gx < 128u) {
            const float* p = base + (quad << 18) + (gy << 7) + gx;
            v.x = p[0];
            v.y = p[1 << 16];
            v.z = p[2 << 16];
            v.w = p[3 << 16];
          }
          *(float4*)&m_s[quad][y][xi + 1][0] = v;
        }
      }
    }
    __syncthreads();

    float q0[8];
#pragma unroll
    for (int k = 0; k < 8; ++k)
      q0[k] = q_in[((b * 64 + cc * 8 + k) << 14) + (h << 7) + w];
#pragma unroll
    for (int dy = 0; dy < 7; ++dy)
#pragma unroll
      for (int dx = 0; dx < 7; ++dx) {
        const float4 m0 = *(const float4*)&m_s[0][ty + dy][tx + 1 + dx][0];
        const float4 m1 = *(const float4*)&m_s[1][ty + dy][tx + 1 + dx][0];
        acc[dy * 7 + dx] += q0[0]*m0.x + q0[1]*m0.y + q0[2]*m0.z + q0[3]*m0.w
                          + q0[4]*m1.x + q0[5]*m1.y + q0[6]*m1.z + q0[7]*m1.w;
      }
  }

  const int obase = ATTN_OFF + ((b * 196 + t) << 14) + (h << 7) + w;
#pragma unroll
  for (int d = 0; d < 49; ++d)
    out[obase + ((d * 4) << 14)] = acc[d];
}

// ---------------------------------------------------------------------------
// K2 (FROZEN, ~31 us, near BW floor): softmax + packed-attn write into d_ws.
// Packed layout keyed to k3's wave tiling: G = (h>>1)*4 + (w>>5),
// lane = (h&1)*32 + (w&31); element (b,G,t,g,lane) at
// ((b*256+G)*4+t)*13*64 + g*64 + lane   (float4 units, d = 4g+j).
// ---------------------------------------------------------------------------
__global__ __launch_bounds__(256) void k2_softmax(
    float* __restrict__ out, const float* __restrict__ cst,
    float4* __restrict__ ws)
{
  const int tid = threadIdx.x;
  const int pl = tid & 63;             // pixel within block
  const int t  = tid >> 6;
  const int pix = blockIdx.x * 64 + pl;      // 65536 pixels total
  const int b = pix >> 14, hw = pix & 16383;
  float* base = out + ATTN_OFF + ((b * 196 + t) << 14) + hw;

  float v[49];
#pragma unroll
  for (int d = 0; d < 49; ++d) v[d] = base[(d * 4) << 14];

  float mx = -1e30f;
#pragma unroll
  for (int d = 0; d < 49; ++d) mx = fmaxf(mx, v[d]);

  __shared__ float red[4][64];
  red[t][pl] = mx;
  __syncthreads();
  float M = fmaxf(fmaxf(red[0][pl], red[1][pl]), fmaxf(red[2][pl], red[3][pl]));
  M = fmaxf(M, cst[0]);
  __syncthreads();

  float s = 0.f;
#pragma unroll
  for (int d = 0; d < 49; ++d) { v[d] = __expf(v[d] - M); s += v[d]; }
  red[t][pl] = s;
  __syncthreads();
  const float l = red[0][pl] + red[1][pl] + red[2][pl] + red[3][pl]
                + __expf(cst[0] - M);
  const float inv = 1.f / l;
#pragma unroll
  for (int d = 0; d < 49; ++d) {
    const float r = v[d] * inv;
    base[(d * 4) << 14] = r;           // reference-layout output (validated)
    v[d] = r;
  }

  if (ws) {
    const int h = hw >> 7, wc = hw & 127;
    const int G    = ((h >> 1) << 2) + (wc >> 5);
    const int lane = ((h & 1) << 5) + (wc & 31);
    float4* dst = ws + (size_t)(((b * 256 + G) * 4 + t) * 13) * 64 + lane;
#pragma unroll
    for (int g = 0; g < 13; ++g) {
      float4 p;
      p.x = v[g * 4];
      p.y = (g < 12) ? v[g * 4 + 1] : 0.f;
      p.z = (g < 12) ? v[g * 4 + 2] : 0.f;
      p.w = (g < 12) ? v[g * 4 + 3] : 0.f;
      dst[g * 64] = p;
    }
  }
}

// ---------------------------------------------------------------------------
// K3 v5 (FROZEN, ~45 us ~= LDS floor): 8-channel blocks, 4 blocks/CU,
// conflict-free staging, g-pipelined coalesced ws reads.
// ---------------------------------------------------------------------------
__global__ __launch_bounds__(256) void k3_read_ws(
    const float* __restrict__ m_out, float* __restrict__ out,
    const float4* __restrict__ ws)
{
  const int b = blockIdx.z >> 3, cq = blockIdx.z & 7;   // 8 ch per group
  const int h0 = blockIdx.y * 8, w0 = blockIdx.x * 32;
  const int tid = threadIdx.x;
  const int tx = tid & 31, ty = tid >> 5;
  const int h = h0 + ty, w = w0 + tx;
  const int waveid = tid >> 6, lane = tid & 63;
  const int G = ((h0 >> 1) + waveid) * 4 + blockIdx.x;

  __shared__ float m_s[2][14][42][4];  // 18,816 B

  float acc[8];
#pragma unroll
  for (int i = 0; i < 8; ++i) acc[i] = 0.f;

#pragma unroll 1
  for (int t = 0; t < 4; ++t) {
    const float4* ap = ws + (size_t)(((b * 256 + G) * 4 + t) * 13) * 64 + lane;

    __syncthreads();                   // prev iter's reads complete
    {
      // 1064 items = 2 quads x 14 rows x 38 xi ; gather -> one b128 write
      const float* base = m_out + (((b * 64 + cq * 8) * 4 + t) << 14);
#pragma unroll
      for (int k = 0; k < 5; ++k) {
        const int item = tid + (k << 8);
        if (item < 1064) {
          const int quad = item >= 532;
          const int rem  = item - 532 * quad;
          const int y  = rem / 38;
          const int xi = rem - 38 * y;
          const int gy = h0 - 3 + y, gx = w0 - 3 + xi;
          float4 v = make_float4(0.f, 0.f, 0.f, 0.f);
          if ((unsigned)gy < 128u && (unsigned)gx < 128u) {
            const float* p = base + (quad << 18) + (gy << 7) + gx;
            v.x = p[0];
            v.y = p[1 << 16];
            v.z = p[2 << 16];
            v.w = p[3 << 16];
          }
          *(float4*)&m_s[quad][y][xi + 1][0] = v;
        }
      }
    }
    __syncthreads();

    float4 cur = ap[0];
#pragma unroll
    for (int g = 0; g < 13; ++g) {
      float4 nxt = cur;
      if (g < 12) nxt = ap[(g + 1) * 64];
#pragma unroll
      for (int j = 0; j < 4; ++j) {
        const int d = g * 4 + j;
        if (d >= 49) break;
        const int dy = d / 7, dx = d % 7;
        const float av = (j == 0) ? cur.x : (j == 1) ? cur.y
                       : (j == 2) ? cur.z : cur.w;
#pragma unroll
        for (int q = 0; q < 2; ++q) {
          const float4 mv = *(const float4*)&m_s[q][ty + dy][tx + dx + 1][0];
          acc[q * 4 + 0] += av * mv.x;
          acc[q * 4 + 1] += av * mv.y;
          acc[q * 4 + 2] += av * mv.z;
          acc[q * 4 + 3] += av * mv.w;
        }
      }
      cur = nxt;
    }
  }

#pragma unroll
  for (int q = 0; q < 2; ++q)
#pragma unroll
    for (int k = 0; k < 4; ++k)
      out[((b * 64 + cq * 8 + q * 4 + k) << 14) + (h << 7) + w] = acc[q * 4 + k];
}

// ---------------------------------------------------------------------------
// K3 fallback (unchanged) — used only if ws_size is too small.
// ---------------------------------------------------------------------------
__global__ __launch_bounds__(256) void k3_read_fb(
    const float* __restrict__ m_out, float* __restrict__ out)
{
  const int b = blockIdx.z >> 2, cq = blockIdx.z & 3;
  const int h0 = blockIdx.y * 8, w0 = blockIdx.x * 32;
  const int tid = threadIdx.x;
  const int tx = tid & 31, ty = tid >> 5;
  const int h = h0 + ty, w = w0 + tx;

  __shared__ float m_s[4][14][38][4];
  const float* __restrict__ attn = out + ATTN_OFF;

  float acc[16];
#pragma unroll
  for (int i = 0; i < 16; ++i) acc[i] = 0.f;

#pragma unroll 1
  for (int t = 0; t < 4; ++t) {
    float a[49];
#pragma unroll
    for (int d = 0; d < 49; ++d)
      a[d] = attn[((b * 196 + d * 4 + t) << 14) + (h << 7) + w];

    __syncthreads();
    for (int e = tid; e < 8512; e += 256) {
      int c16 = e / 532; int rem = e - c16 * 532;
      int y = rem / 38;  int x = rem - y * 38;
      int gy = h0 - 3 + y, gx = w0 - 3 + x;
      float v = 0.f;
      if (gy >= 0 && gy < 128 && gx >= 0 && gx < 128)
        v = m_out[(((b * 64 + cq * 16 + c16) * 4 + t) << 14) + (gy << 7) + gx];
      m_s[c16 >> 2][y][x][c16 & 3] = v;
    }
    __syncthreads();

#pragma unroll
    for (int dy = 0; dy < 7; ++dy)
#pragma unroll
      for (int dx = 0; dx < 7; ++dx) {
        const float av = a[dy * 7 + dx];
#pragma unroll
        for (int q = 0; q < 4; ++q) {
          const float4 mv = *(const float4*)&m_s[q][ty + dy][tx + dx][0];
          acc[q * 4 + 0] += av * mv.x;
          acc[q * 4 + 1] += av * mv.y;
          acc[q * 4 + 2] += av * mv.z;
          acc[q * 4 + 3] += av * mv.w;
        }
      }
  }

#pragma unroll
  for (int q = 0; q < 4; ++q)
#pragma unroll
    for (int k = 0; k < 4; ++k)
      out[((b * 64 + cq * 16 + q * 4 + k) << 14) + (h << 7) + w] = acc[q * 4 + k];
}

extern "C" void kernel_launch(void* const* d_in, const int* in_sizes, int n_in,
                              void* d_out, int out_size, void* d_ws, size_t ws_size,
                              hipStream_t stream) {
  const float* m_in  = (const float*)d_in[0];
  const float* m_out = (const float*)d_in[1];
  const float* q_in  = (const float*)d_in[2];
  const float* cst   = (const float*)d_in[3];
  float* out = (float*)d_out;

  const bool use_ws = (ws_size >= WS_F4_COUNT * 16ull) && d_ws != nullptr;
  float4* ws = use_ws ? (float4*)d_ws : nullptr;

  k1_corr<<<dim3(4, 16, 16), dim3(256), 0, stream>>>(m_in, q_in, out);
  k2_softmax<<<dim3(1024), dim3(256), 0, stream>>>(out, cst, ws);
  if (use_ws)
    k3_read_ws<<<dim3(4, 16, 32), dim3(256), 0, stream>>>(m_out, out, ws);
  else
    k3_read_fb<<<dim3(4, 16, 16), dim3(256), 0, stream>>>(m_out, out);
}

// Round 11
// 148.478 us; speedup vs baseline: 1.1143x; 1.1143x over previous
//
#include <hip/hip_runtime.h>

// Problem constants: B=4, De=Do=64, T=4, H=W=128, PATCH=7, R=3
#define ATTN_OFF 4194304                 // B*Do*H*W (mem region size in floats)
// packed attn ws: [b][G=256][t][13][64] float4  = 3,407,872 float4s
#define WS_F4_COUNT 3407872ull

// ---------------------------------------------------------------------------
// K1 v10: v8 structure (proven 75 us) + bijective XCD swizzle.
//  - v8: tile 32x8, 1 px/thread, 16 chunks x 4 channels, LDS 9,408 B ->
//    4 blocks/CU resident (R10 proved bigger LDS kills residency: 18.9 KB
//    -> 2 blocks/CU -> 98 us).
//  - swizzle: physical p = x+4y+64z round-robins XCDs by p%8. Remap
//    l = (p%8)*128 + p/8 so each XCD owns a contiguous logical range:
//    y-adjacent tiles (6 shared halo rows) then run on the SAME XCD ~4
//    blocks apart -> halo re-fetch becomes L2 hits instead of HBM (R9's
//    FETCH=148MB = 2.2x m_in shows halos currently miss L2).
//  - pure work permutation: numerics identical.
// ---------------------------------------------------------------------------
__global__ __launch_bounds__(256) void k1_corr(
    const float* __restrict__ m_in, const float* __restrict__ q_in,
    float* __restrict__ out)
{
  // physical linear id -> logical tile id (bijective, 1024 % 8 == 0)
  const int p = blockIdx.x + (blockIdx.y << 2) + (blockIdx.z << 6);
  const int l = ((p & 7) << 7) + (p >> 3);
  const int bx = l & 3, by = (l >> 2) & 15, bz = l >> 6;

  const int b = bz >> 2, t = bz & 3;
  const int h0 = by * 8, w0 = bx * 32;
  const int tid = threadIdx.x;
  const int tx = tid & 31, ty = tid >> 5;
  const int h = h0 + ty, w = w0 + tx;

  // [y 0..13][x 0..41][c%4]; slot xi+1 <-> gx = w0-3+xi
  __shared__ float m_s[14][42][4];      // 9,408 B

  float acc[49];
#pragma unroll
  for (int d = 0; d < 49; ++d) acc[d] = 0.f;

#pragma unroll 1
  for (int cc = 0; cc < 16; ++cc) {     // 16 chunks x 4 channels
    __syncthreads();                    // prev chunk's reads complete
    {
      // 532 items = 14 rows x 38 xi ; 4-channel gather -> one b128 write
      const float* base = m_in + (((b * 64 + cc * 4) * 4 + t) << 14);
#pragma unroll
      for (int k = 0; k < 3; ++k) {
        const int item = tid + (k << 8);
        if (item < 532) {
          const int y  = item / 38;             // magic-mul
          const int xi = item - 38 * y;
          const int gy = h0 - 3 + y, gx = w0 - 3 + xi;
          float4 v = make_float4(0.f, 0.f, 0.f, 0.f);
          if ((unsigned)gy < 128u && (unsigned)gx < 128u) {
            const float* p2 = base + (gy << 7) + gx;
            v.x = p2[0];
            v.y = p2[1 << 16];
            v.z = p2[2 << 16];
            v.w = p2[3 << 16];
          }
          *(float4*)&m_s[y][xi + 1][0] = v;
        }
      }
    }
    __syncthreads();

    float q0[4];
#pragma unroll
    for (int k = 0; k < 4; ++k)
      q0[k] = q_in[((b * 64 + cc * 4 + k) << 14) + (h << 7) + w];
#pragma unroll
    for (int dy = 0; dy < 7; ++dy)
#pragma unroll
      for (int dx = 0; dx < 7; ++dx) {
        const float4 mv = *(const float4*)&m_s[ty + dy][tx + 1 + dx][0];
        acc[dy * 7 + dx] += q0[0]*mv.x + q0[1]*mv.y + q0[2]*mv.z + q0[3]*mv.w;
      }
  }

  const int obase = ATTN_OFF + ((b * 196 + t) << 14) + (h << 7) + w;
#pragma unroll
  for (int d = 0; d < 49; ++d)
    out[obase + ((d * 4) << 14)] = acc[d];
}

// ---------------------------------------------------------------------------
// K2 (FROZEN, ~31 us, near BW floor): softmax + packed-attn write into d_ws.
// Packed layout keyed to k3's wave tiling: G = (h>>1)*4 + (w>>5),
// lane = (h&1)*32 + (w&31); element (b,G,t,g,lane) at
// ((b*256+G)*4+t)*13*64 + g*64 + lane   (float4 units, d = 4g+j).
// ---------------------------------------------------------------------------
__global__ __launch_bounds__(256) void k2_softmax(
    float* __restrict__ out, const float* __restrict__ cst,
    float4* __restrict__ ws)
{
  const int tid = threadIdx.x;
  const int pl = tid & 63;             // pixel within block
  const int t  = tid >> 6;
  const int pix = blockIdx.x * 64 + pl;      // 65536 pixels total
  const int b = pix >> 14, hw = pix & 16383;
  float* base = out + ATTN_OFF + ((b * 196 + t) << 14) + hw;

  float v[49];
#pragma unroll
  for (int d = 0; d < 49; ++d) v[d] = base[(d * 4) << 14];

  float mx = -1e30f;
#pragma unroll
  for (int d = 0; d < 49; ++d) mx = fmaxf(mx, v[d]);

  __shared__ float red[4][64];
  red[t][pl] = mx;
  __syncthreads();
  float M = fmaxf(fmaxf(red[0][pl], red[1][pl]), fmaxf(red[2][pl], red[3][pl]));
  M = fmaxf(M, cst[0]);
  __syncthreads();

  float s = 0.f;
#pragma unroll
  for (int d = 0; d < 49; ++d) { v[d] = __expf(v[d] - M); s += v[d]; }
  red[t][pl] = s;
  __syncthreads();
  const float l = red[0][pl] + red[1][pl] + red[2][pl] + red[3][pl]
                + __expf(cst[0] - M);
  const float inv = 1.f / l;
#pragma unroll
  for (int d = 0; d < 49; ++d) {
    const float r = v[d] * inv;
    base[(d * 4) << 14] = r;           // reference-layout output (validated)
    v[d] = r;
  }

  if (ws) {
    const int h = hw >> 7, wc = hw & 127;
    const int G    = ((h >> 1) << 2) + (wc >> 5);
    const int lane = ((h & 1) << 5) + (wc & 31);
    float4* dst = ws + (size_t)(((b * 256 + G) * 4 + t) * 13) * 64 + lane;
#pragma unroll
    for (int g = 0; g < 13; ++g) {
      float4 p;
      p.x = v[g * 4];
      p.y = (g < 12) ? v[g * 4 + 1] : 0.f;
      p.z = (g < 12) ? v[g * 4 + 2] : 0.f;
      p.w = (g < 12) ? v[g * 4 + 3] : 0.f;
      dst[g * 64] = p;
    }
  }
}

// ---------------------------------------------------------------------------
// K3 v5 (FROZEN, ~45 us ~= LDS floor): 8-channel blocks, high occupancy,
// conflict-free staging, g-pipelined coalesced ws reads.
// ---------------------------------------------------------------------------
__global__ __launch_bounds__(256) void k3_read_ws(
    const float* __restrict__ m_out, float* __restrict__ out,
    const float4* __restrict__ ws)
{
  const int b = blockIdx.z >> 3, cq = blockIdx.z & 7;   // 8 ch per group
  const int h0 = blockIdx.y * 8, w0 = blockIdx.x * 32;
  const int tid = threadIdx.x;
  const int tx = tid & 31, ty = tid >> 5;
  const int h = h0 + ty, w = w0 + tx;
  const int waveid = tid >> 6, lane = tid & 63;
  const int G = ((h0 >> 1) + waveid) * 4 + blockIdx.x;

  __shared__ float m_s[2][14][42][4];  // 18,816 B

  float acc[8];
#pragma unroll
  for (int i = 0; i < 8; ++i) acc[i] = 0.f;

#pragma unroll 1
  for (int t = 0; t < 4; ++t) {
    const float4* ap = ws + (size_t)(((b * 256 + G) * 4 + t) * 13) * 64 + lane;

    __syncthreads();                   // prev iter's reads complete
    {
      // 1064 items = 2 quads x 14 rows x 38 xi ; gather -> one b128 write
      const float* base = m_out + (((b * 64 + cq * 8) * 4 + t) << 14);
#pragma unroll
      for (int k = 0; k < 5; ++k) {
        const int item = tid + (k << 8);
        if (item < 1064) {
          const int quad = item >= 532;
          const int rem  = item - 532 * quad;
          const int y  = rem / 38;
          const int xi = rem - 38 * y;
          const int gy = h0 - 3 + y, gx = w0 - 3 + xi;
          float4 v = make_float4(0.f, 0.f, 0.f, 0.f);
          if ((unsigned)gy < 128u && (unsigned)gx < 128u) {
            const float* p = base + (quad << 18) + (gy << 7) + gx;
            v.x = p[0];
            v.y = p[1 << 16];
            v.z = p[2 << 16];
            v.w = p[3 << 16];
          }
          *(float4*)&m_s[quad][y][xi + 1][0] = v;
        }
      }
    }
    __syncthreads();

    float4 cur = ap[0];
#pragma unroll
    for (int g = 0; g < 13; ++g) {
      float4 nxt = cur;
      if (g < 12) nxt = ap[(g + 1) * 64];
#pragma unroll
      for (int j = 0; j < 4; ++j) {
        const int d = g * 4 + j;
        if (d >= 49) break;
        const int dy = d / 7, dx = d % 7;
        const float av = (j == 0) ? cur.x : (j == 1) ? cur.y
                       : (j == 2) ? cur.z : cur.w;
#pragma unroll
        for (int q = 0; q < 2; ++q) {
          const float4 mv = *(const float4*)&m_s[q][ty + dy][tx + dx + 1][0];
          acc[q * 4 + 0] += av * mv.x;
          acc[q * 4 + 1] += av * mv.y;
          acc[q * 4 + 2] += av * mv.z;
          acc[q * 4 + 3] += av * mv.w;
        }
      }
      cur = nxt;
    }
  }

#pragma unroll
  for (int q = 0; q < 2; ++q)
#pragma unroll
    for (int k = 0; k < 4; ++k)
      out[((b * 64 + cq * 8 + q * 4 + k) << 14) + (h << 7) + w] = acc[q * 4 + k];
}

// ---------------------------------------------------------------------------
// K3 fallback (unchanged) — used only if ws_size is too small.
// ---------------------------------------------------------------------------
__global__ __launch_bounds__(256) void k3_read_fb(
    const float* __restrict__ m_out, float* __restrict__ out)
{
  const int b = blockIdx.z >> 2, cq = blockIdx.z & 3;
  const int h0 = blockIdx.y * 8, w0 = blockIdx.x * 32;
  const int tid = threadIdx.x;
  const int tx = tid & 31, ty = tid >> 5;
  const int h = h0 + ty, w = w0 + tx;

  __shared__ float m_s[4][14][38][4];
  const float* __restrict__ attn = out + ATTN_OFF;

  float acc[16];
#pragma unroll
  for (int i = 0; i < 16; ++i) acc[i] = 0.f;

#pragma unroll 1
  for (int t = 0; t < 4; ++t) {
    float a[49];
#pragma unroll
    for (int d = 0; d < 49; ++d)
      a[d] = attn[((b * 196 + d * 4 + t) << 14) + (h << 7) + w];

    __syncthreads();
    for (int e = tid; e < 8512; e += 256) {
      int c16 = e / 532; int rem = e - c16 * 532;
      int y = rem / 38;  int x = rem - y * 38;
      int gy = h0 - 3 + y, gx = w0 - 3 + x;
      float v = 0.f;
      if (gy >= 0 && gy < 128 && gx >= 0 && gx < 128)
        v = m_out[(((b * 64 + cq * 16 + c16) * 4 + t) << 14) + (gy << 7) + gx];
      m_s[c16 >> 2][y][x][c16 & 3] = v;
    }
    __syncthreads();

#pragma unroll
    for (int dy = 0; dy < 7; ++dy)
#pragma unroll
      for (int dx = 0; dx < 7; ++dx) {
        const float av = a[dy * 7 + dx];
#pragma unroll
        for (int q = 0; q < 4; ++q) {
          const float4 mv = *(const float4*)&m_s[q][ty + dy][tx + dx][0];
          acc[q * 4 + 0] += av * mv.x;
          acc[q * 4 + 1] += av * mv.y;
          acc[q * 4 + 2] += av * mv.z;
          acc[q * 4 + 3] += av * mv.w;
        }
      }
  }

#pragma unroll
  for (int q = 0; q < 4; ++q)
#pragma unroll
    for (int k = 0; k < 4; ++k)
      out[((b * 64 + cq * 16 + q * 4 + k) << 14) + (h << 7) + w] = acc[q * 4 + k];
}

extern "C" void kernel_launch(void* const* d_in, const int* in_sizes, int n_in,
                              void* d_out, int out_size, void* d_ws, size_t ws_size,
                              hipStream_t stream) {
  const float* m_in  = (const float*)d_in[0];
  const float* m_out = (const float*)d_in[1];
  const float* q_in  = (const float*)d_in[2];
  const float* cst   = (const float*)d_in[3];
  float* out = (float*)d_out;

  const bool use_ws = (ws_size >= WS_F4_COUNT * 16ull) && d_ws != nullptr;
  float4* ws = use_ws ? (float4*)d_ws : nullptr;

  k1_corr<<<dim3(4, 16, 16), dim3(256), 0, stream>>>(m_in, q_in, out);
  k2_softmax<<<dim3(1024), dim3(256), 0, stream>>>(out, cst, ws);
  if (use_ws)
    k3_read_ws<<<dim3(4, 16, 32), dim3(256), 0, stream>>>(m_out, out, ws);
  else
    k3_read_fb<<<dim3(4, 16, 16), dim3(256), 0, stream>>>(m_out, out);
}

// Round 12
// 142.222 us; speedup vs baseline: 1.1633x; 1.0440x over previous
//
#include <hip/hip_runtime.h>

// Problem constants: B=4, De=Do=64, T=4, H=W=128, PATCH=7, R=3
#define ATTN_OFF 4194304                 // B*Do*H*W (mem region size in floats)
// packed attn ws: [b][G=256][t][13][64] float4  = 3,407,872 float4s
#define WS_F4_COUNT 3407872ull

// ---------------------------------------------------------------------------
// K1 v11: v8 structure + early-issue/write-late staging pipeline.
//  - v8 core: tile 32x8, 1 px/thread, 16 chunks x 4 channels, single 9,408 B
//    LDS buffer (4 blocks/CU), conflict-free b128 staging, XCD swizzle.
//  - pipeline: per phase [bar -> write held regs -> bar -> ISSUE next loads
//    -> compute]. The vmcnt wait for the loads lands at the NEXT phase's
//    write, hidden under a full compute phase. (R11 proved locality isn't
//    the cost: FETCH 148->50 MB, time unchanged -> it's the per-phase
//    exposed load-wait.)
//  - in-flight = 12 VGPR (vs R5's 60 which spilled at 98-float acc; here
//    acc=49 -> ~90-110 total, safe under 128).
//  - decomposition (y,xi,clamped goff,LDS off,mask) hoisted, computed once.
//  - mask-multiply at write -> exact zeros, channel order unchanged:
//    numerics identical.
// ---------------------------------------------------------------------------
__global__ __launch_bounds__(256, 2) void k1_corr(
    const float* __restrict__ m_in, const float* __restrict__ q_in,
    float* __restrict__ out)
{
  // bijective XCD swizzle (1024 % 8 == 0)
  const int p = blockIdx.x + (blockIdx.y << 2) + (blockIdx.z << 6);
  const int l = ((p & 7) << 7) + (p >> 3);
  const int bx = l & 3, by = (l >> 2) & 15, bz = l >> 6;

  const int b = bz >> 2, t = bz & 3;
  const int h0 = by * 8, w0 = bx * 32;
  const int tid = threadIdx.x;
  const int tx = tid & 31, ty = tid >> 5;
  const int h = h0 + ty, w = w0 + tx;

  // [y 0..13][x 0..41][c%4]; slot xi+1 <-> gx = w0-3+xi
  __shared__ float m_s[14][42][4];      // 9,408 B
  float* const lds = &m_s[0][0][0];

  float acc[49];
#pragma unroll
  for (int d = 0; d < 49; ++d) acc[d] = 0.f;

  // ---- chunk-invariant decomposition (532 items = 14 rows x 38 xi) ----
  // item0 = tid (always), item1 = tid+256 (always), item2 = tid+512 (tid<20)
  int goff0, goff1, goff2, loff0, loff1, loff2;
  float msk0, msk1, msk2;
  {
    const int i0 = tid;
    const int y0 = i0 / 38, x0 = i0 - 38 * y0;
    const int gy0 = h0 - 3 + y0, gx0 = w0 - 3 + x0;
    msk0 = (((unsigned)gy0 < 128u) && ((unsigned)gx0 < 128u)) ? 1.f : 0.f;
    const int gyc0 = gy0 < 0 ? 0 : (gy0 > 127 ? 127 : gy0);
    const int gxc0 = gx0 < 0 ? 0 : (gx0 > 127 ? 127 : gx0);
    goff0 = (gyc0 << 7) + gxc0;
    loff0 = (y0 * 42 + x0 + 1) << 2;

    const int i1 = tid + 256;
    const int y1 = i1 / 38, x1 = i1 - 38 * y1;
    const int gy1 = h0 - 3 + y1, gx1 = w0 - 3 + x1;
    msk1 = (((unsigned)gy1 < 128u) && ((unsigned)gx1 < 128u)) ? 1.f : 0.f;
    const int gyc1 = gy1 < 0 ? 0 : (gy1 > 127 ? 127 : gy1);
    const int gxc1 = gx1 < 0 ? 0 : (gx1 > 127 ? 127 : gx1);
    goff1 = (gyc1 << 7) + gxc1;
    loff1 = (y1 * 42 + x1 + 1) << 2;

    const int i2 = tid + 512;                 // valid only for tid < 20
    const int i2c = i2 < 532 ? i2 : 531;
    const int y2 = i2c / 38, x2 = i2c - 38 * y2;
    const int gy2 = h0 - 3 + y2, gx2 = w0 - 3 + x2;
    msk2 = (((unsigned)gy2 < 128u) && ((unsigned)gx2 < 128u)) ? 1.f : 0.f;
    const int gyc2 = gy2 < 0 ? 0 : (gy2 > 127 ? 127 : gy2);
    const int gxc2 = gx2 < 0 ? 0 : (gx2 > 127 ? 127 : gx2);
    goff2 = (gyc2 << 7) + gxc2;
    loff2 = (y2 * 42 + x2 + 1) << 2;
  }
  const bool has2 = (tid < 20);

  // ---- prologue: load chunk 0 into held regs ----
  float4 r0, r1, r2;
  {
    const float* base = m_in + ((b * 256 + t) << 14);   // cc = 0
    const float* p0 = base + goff0;
    r0.x = p0[0]; r0.y = p0[65536]; r0.z = p0[131072]; r0.w = p0[196608];
    const float* p1 = base + goff1;
    r1.x = p1[0]; r1.y = p1[65536]; r1.z = p1[131072]; r1.w = p1[196608];
    r2 = make_float4(0.f, 0.f, 0.f, 0.f);
    if (has2) {
      const float* p2 = base + goff2;
      r2.x = p2[0]; r2.y = p2[65536]; r2.z = p2[131072]; r2.w = p2[196608];
    }
  }

#pragma unroll 1
  for (int cc = 0; cc < 16; ++cc) {     // 16 chunks x 4 channels
    __syncthreads();                    // prev phase's reads complete
    *(float4*)(lds + loff0) = make_float4(r0.x*msk0, r0.y*msk0, r0.z*msk0, r0.w*msk0);
    *(float4*)(lds + loff1) = make_float4(r1.x*msk1, r1.y*msk1, r1.z*msk1, r1.w*msk1);
    if (has2)
      *(float4*)(lds + loff2) = make_float4(r2.x*msk2, r2.y*msk2, r2.z*msk2, r2.w*msk2);
    __syncthreads();                    // writes visible

    if (cc < 15) {                      // issue next chunk's loads (no wait)
      const float* base = m_in + (((b * 64 + (cc + 1) * 4) * 4 + t) << 14);
      const float* p0 = base + goff0;
      r0.x = p0[0]; r0.y = p0[65536]; r0.z = p0[131072]; r0.w = p0[196608];
      const float* p1 = base + goff1;
      r1.x = p1[0]; r1.y = p1[65536]; r1.z = p1[131072]; r1.w = p1[196608];
      if (has2) {
        const float* p2 = base + goff2;
        r2.x = p2[0]; r2.y = p2[65536]; r2.z = p2[131072]; r2.w = p2[196608];
      }
    }

    float q0[4];
#pragma unroll
    for (int k = 0; k < 4; ++k)
      q0[k] = q_in[((b * 64 + cc * 4 + k) << 14) + (h << 7) + w];
#pragma unroll
    for (int dy = 0; dy < 7; ++dy)
#pragma unroll
      for (int dx = 0; dx < 7; ++dx) {
        const float4 mv = *(const float4*)&m_s[ty + dy][tx + 1 + dx][0];
        acc[dy * 7 + dx] += q0[0]*mv.x + q0[1]*mv.y + q0[2]*mv.z + q0[3]*mv.w;
      }
  }

  const int obase = ATTN_OFF + ((b * 196 + t) << 14) + (h << 7) + w;
#pragma unroll
  for (int d = 0; d < 49; ++d)
    out[obase + ((d * 4) << 14)] = acc[d];
}

// ---------------------------------------------------------------------------
// K2 (FROZEN, ~31 us, near BW floor): softmax + packed-attn write into d_ws.
// Packed layout keyed to k3's wave tiling: G = (h>>1)*4 + (w>>5),
// lane = (h&1)*32 + (w&31); element (b,G,t,g,lane) at
// ((b*256+G)*4+t)*13*64 + g*64 + lane   (float4 units, d = 4g+j).
// ---------------------------------------------------------------------------
__global__ __launch_bounds__(256) void k2_softmax(
    float* __restrict__ out, const float* __restrict__ cst,
    float4* __restrict__ ws)
{
  const int tid = threadIdx.x;
  const int pl = tid & 63;             // pixel within block
  const int t  = tid >> 6;
  const int pix = blockIdx.x * 64 + pl;      // 65536 pixels total
  const int b = pix >> 14, hw = pix & 16383;
  float* base = out + ATTN_OFF + ((b * 196 + t) << 14) + hw;

  float v[49];
#pragma unroll
  for (int d = 0; d < 49; ++d) v[d] = base[(d * 4) << 14];

  float mx = -1e30f;
#pragma unroll
  for (int d = 0; d < 49; ++d) mx = fmaxf(mx, v[d]);

  __shared__ float red[4][64];
  red[t][pl] = mx;
  __syncthreads();
  float M = fmaxf(fmaxf(red[0][pl], red[1][pl]), fmaxf(red[2][pl], red[3][pl]));
  M = fmaxf(M, cst[0]);
  __syncthreads();

  float s = 0.f;
#pragma unroll
  for (int d = 0; d < 49; ++d) { v[d] = __expf(v[d] - M); s += v[d]; }
  red[t][pl] = s;
  __syncthreads();
  const float l = red[0][pl] + red[1][pl] + red[2][pl] + red[3][pl]
                + __expf(cst[0] - M);
  const float inv = 1.f / l;
#pragma unroll
  for (int d = 0; d < 49; ++d) {
    const float r = v[d] * inv;
    base[(d * 4) << 14] = r;           // reference-layout output (validated)
    v[d] = r;
  }

  if (ws) {
    const int h = hw >> 7, wc = hw & 127;
    const int G    = ((h >> 1) << 2) + (wc >> 5);
    const int lane = ((h & 1) << 5) + (wc & 31);
    float4* dst = ws + (size_t)(((b * 256 + G) * 4 + t) * 13) * 64 + lane;
#pragma unroll
    for (int g = 0; g < 13; ++g) {
      float4 p;
      p.x = v[g * 4];
      p.y = (g < 12) ? v[g * 4 + 1] : 0.f;
      p.z = (g < 12) ? v[g * 4 + 2] : 0.f;
      p.w = (g < 12) ? v[g * 4 + 3] : 0.f;
      dst[g * 64] = p;
    }
  }
}

// ---------------------------------------------------------------------------
// K3 v5 (FROZEN, ~45 us ~= LDS floor): 8-channel blocks, conflict-free
// staging, g-pipelined coalesced ws reads.
// ---------------------------------------------------------------------------
__global__ __launch_bounds__(256) void k3_read_ws(
    const float* __restrict__ m_out, float* __restrict__ out,
    const float4* __restrict__ ws)
{
  const int b = blockIdx.z >> 3, cq = blockIdx.z & 7;   // 8 ch per group
  const int h0 = blockIdx.y * 8, w0 = blockIdx.x * 32;
  const int tid = threadIdx.x;
  const int tx = tid & 31, ty = tid >> 5;
  const int h = h0 + ty, w = w0 + tx;
  const int waveid = tid >> 6, lane = tid & 63;
  const int G = ((h0 >> 1) + waveid) * 4 + blockIdx.x;

  __shared__ float m_s[2][14][42][4];  // 18,816 B

  float acc[8];
#pragma unroll
  for (int i = 0; i < 8; ++i) acc[i] = 0.f;

#pragma unroll 1
  for (int t = 0; t < 4; ++t) {
    const float4* ap = ws + (size_t)(((b * 256 + G) * 4 + t) * 13) * 64 + lane;

    __syncthreads();                   // prev iter's reads complete
    {
      // 1064 items = 2 quads x 14 rows x 38 xi ; gather -> one b128 write
      const float* base = m_out + (((b * 64 + cq * 8) * 4 + t) << 14);
#pragma unroll
      for (int k = 0; k < 5; ++k) {
        const int item = tid + (k << 8);
        if (item < 1064) {
          const int quad = item >= 532;
          const int rem  = item - 532 * quad;
          const int y  = rem / 38;
          const int xi = rem - 38 * y;
          const int gy = h0 - 3 + y, gx = w0 - 3 + xi;
          float4 v = make_float4(0.f, 0.f, 0.f, 0.f);
          if ((unsigned)gy < 128u && (unsigned)gx < 128u) {
            const float* p = base + (quad << 18) + (gy << 7) + gx;
            v.x = p[0];
            v.y = p[1 << 16];
            v.z = p[2 << 16];
            v.w = p[3 << 16];
          }
          *(float4*)&m_s[quad][y][xi + 1][0] = v;
        }
      }
    }
    __syncthreads();

    float4 cur = ap[0];
#pragma unroll
    for (int g = 0; g < 13; ++g) {
      float4 nxt = cur;
      if (g < 12) nxt = ap[(g + 1) * 64];
#pragma unroll
      for (int j = 0; j < 4; ++j) {
        const int d = g * 4 + j;
        if (d >= 49) break;
        const int dy = d / 7, dx = d % 7;
        const float av = (j == 0) ? cur.x : (j == 1) ? cur.y
                       : (j == 2) ? cur.z : cur.w;
#pragma unroll
        for (int q = 0; q < 2; ++q) {
          const float4 mv = *(const float4*)&m_s[q][ty + dy][tx + dx + 1][0];
          acc[q * 4 + 0] += av * mv.x;
          acc[q * 4 + 1] += av * mv.y;
          acc[q * 4 + 2] += av * mv.z;
          acc[q * 4 + 3] += av * mv.w;
        }
      }
      cur = nxt;
    }
  }

#pragma unroll
  for (int q = 0; q < 2; ++q)
#pragma unroll
    for (int k = 0; k < 4; ++k)
      out[((b * 64 + cq * 8 + q * 4 + k) << 14) + (h << 7) + w] = acc[q * 4 + k];
}

// ---------------------------------------------------------------------------
// K3 fallback (unchanged) — used only if ws_size is too small.
// ---------------------------------------------------------------------------
__global__ __launch_bounds__(256) void k3_read_fb(
    const float* __restrict__ m_out, float* __restrict__ out)
{
  const int b = blockIdx.z >> 2, cq = blockIdx.z & 3;
  const int h0 = blockIdx.y * 8, w0 = blockIdx.x * 32;
  const int tid = threadIdx.x;
  const int tx = tid & 31, ty = tid >> 5;
  const int h = h0 + ty, w = w0 + tx;

  __shared__ float m_s[4][14][38][4];
  const float* __restrict__ attn = out + ATTN_OFF;

  float acc[16];
#pragma unroll
  for (int i = 0; i < 16; ++i) acc[i] = 0.f;

#pragma unroll 1
  for (int t = 0; t < 4; ++t) {
    float a[49];
#pragma unroll
    for (int d = 0; d < 49; ++d)
      a[d] = attn[((b * 196 + d * 4 + t) << 14) + (h << 7) + w];

    __syncthreads();
    for (int e = tid; e < 8512; e += 256) {
      int c16 = e / 532; int rem = e - c16 * 532;
      int y = rem / 38;  int x = rem - y * 38;
      int gy = h0 - 3 + y, gx = w0 - 3 + x;
      float v = 0.f;
      if (gy >= 0 && gy < 128 && gx >= 0 && gx < 128)
        v = m_out[(((b * 64 + cq * 16 + c16) * 4 + t) << 14) + (gy << 7) + gx];
      m_s[c16 >> 2][y][x][c16 & 3] = v;
    }
    __syncthreads();

#pragma unroll
    for (int dy = 0; dy < 7; ++dy)
#pragma unroll
      for (int dx = 0; dx < 7; ++dx) {
        const float av = a[dy * 7 + dx];
#pragma unroll
        for (int q = 0; q < 4; ++q) {
          const float4 mv = *(const float4*)&m_s[q][ty + dy][tx + dx][0];
          acc[q * 4 + 0] += av * mv.x;
          acc[q * 4 + 1] += av * mv.y;
          acc[q * 4 + 2] += av * mv.z;
          acc[q * 4 + 3] += av * mv.w;
        }
      }
  }

#pragma unroll
  for (int q = 0; q < 4; ++q)
#pragma unroll
    for (int k = 0; k < 4; ++k)
      out[((b * 64 + cq * 16 + q * 4 + k) << 14) + (h << 7) + w] = acc[q * 4 + k];
}

extern "C" void kernel_launch(void* const* d_in, const int* in_sizes, int n_in,
                              void* d_out, int out_size, void* d_ws, size_t ws_size,
                              hipStream_t stream) {
  const float* m_in  = (const float*)d_in[0];
  const float* m_out = (const float*)d_in[1];
  const float* q_in  = (const float*)d_in[2];
  const float* cst   = (const float*)d_in[3];
  float* out = (float*)d_out;

  const bool use_ws = (ws_size >= WS_F4_COUNT * 16ull) && d_ws != nullptr;
  float4* ws = use_ws ? (float4*)d_ws : nullptr;

  k1_corr<<<dim3(4, 16, 16), dim3(256), 0, stream>>>(m_in, q_in, out);
  k2_softmax<<<dim3(1024), dim3(256), 0, stream>>>(out, cst, ws);
  if (use_ws)
    k3_read_ws<<<dim3(4, 16, 32), dim3(256), 0, stream>>>(m_out, out, ws);
  else
    k3_read_fb<<<dim3(4, 16, 16), dim3(256), 0, stream>>>(m_out, out);
}

// Round 13
// 130.590 us; speedup vs baseline: 1.2669x; 1.0891x over previous
//
#include <hip/hip_runtime.h>

// Problem constants: B=4, De=Do=64, T=4, H=W=128, PATCH=7, R=3
#define ATTN_OFF 4194304                 // B*Do*H*W (mem region size in floats)
// packed attn ws: [b][G=256][t][13][64] float4  = 3,407,872 float4s
#define WS_F4_COUNT 3407872ull

// ---------------------------------------------------------------------------
// K1 v11 (FROZEN): v8 structure + XCD swizzle + early-issue/write-late
// staging pipeline. Wall-validated in R12.
// ---------------------------------------------------------------------------
__global__ __launch_bounds__(256, 2) void k1_corr(
    const float* __restrict__ m_in, const float* __restrict__ q_in,
    float* __restrict__ out)
{
  // bijective XCD swizzle (1024 % 8 == 0)
  const int p = blockIdx.x + (blockIdx.y << 2) + (blockIdx.z << 6);
  const int l = ((p & 7) << 7) + (p >> 3);
  const int bx = l & 3, by = (l >> 2) & 15, bz = l >> 6;

  const int b = bz >> 2, t = bz & 3;
  const int h0 = by * 8, w0 = bx * 32;
  const int tid = threadIdx.x;
  const int tx = tid & 31, ty = tid >> 5;
  const int h = h0 + ty, w = w0 + tx;

  __shared__ float m_s[14][42][4];      // 9,408 B
  float* const lds = &m_s[0][0][0];

  float acc[49];
#pragma unroll
  for (int d = 0; d < 49; ++d) acc[d] = 0.f;

  int goff0, goff1, goff2, loff0, loff1, loff2;
  float msk0, msk1, msk2;
  {
    const int i0 = tid;
    const int y0 = i0 / 38, x0 = i0 - 38 * y0;
    const int gy0 = h0 - 3 + y0, gx0 = w0 - 3 + x0;
    msk0 = (((unsigned)gy0 < 128u) && ((unsigned)gx0 < 128u)) ? 1.f : 0.f;
    const int gyc0 = gy0 < 0 ? 0 : (gy0 > 127 ? 127 : gy0);
    const int gxc0 = gx0 < 0 ? 0 : (gx0 > 127 ? 127 : gx0);
    goff0 = (gyc0 << 7) + gxc0;
    loff0 = (y0 * 42 + x0 + 1) << 2;

    const int i1 = tid + 256;
    const int y1 = i1 / 38, x1 = i1 - 38 * y1;
    const int gy1 = h0 - 3 + y1, gx1 = w0 - 3 + x1;
    msk1 = (((unsigned)gy1 < 128u) && ((unsigned)gx1 < 128u)) ? 1.f : 0.f;
    const int gyc1 = gy1 < 0 ? 0 : (gy1 > 127 ? 127 : gy1);
    const int gxc1 = gx1 < 0 ? 0 : (gx1 > 127 ? 127 : gx1);
    goff1 = (gyc1 << 7) + gxc1;
    loff1 = (y1 * 42 + x1 + 1) << 2;

    const int i2 = tid + 512;                 // valid only for tid < 20
    const int i2c = i2 < 532 ? i2 : 531;
    const int y2 = i2c / 38, x2 = i2c - 38 * y2;
    const int gy2 = h0 - 3 + y2, gx2 = w0 - 3 + x2;
    msk2 = (((unsigned)gy2 < 128u) && ((unsigned)gx2 < 128u)) ? 1.f : 0.f;
    const int gyc2 = gy2 < 0 ? 0 : (gy2 > 127 ? 127 : gy2);
    const int gxc2 = gx2 < 0 ? 0 : (gx2 > 127 ? 127 : gx2);
    goff2 = (gyc2 << 7) + gxc2;
    loff2 = (y2 * 42 + x2 + 1) << 2;
  }
  const bool has2 = (tid < 20);

  float4 r0, r1, r2;
  {
    const float* base = m_in + ((b * 256 + t) << 14);   // cc = 0
    const float* p0 = base + goff0;
    r0.x = p0[0]; r0.y = p0[65536]; r0.z = p0[131072]; r0.w = p0[196608];
    const float* p1 = base + goff1;
    r1.x = p1[0]; r1.y = p1[65536]; r1.z = p1[131072]; r1.w = p1[196608];
    r2 = make_float4(0.f, 0.f, 0.f, 0.f);
    if (has2) {
      const float* p2 = base + goff2;
      r2.x = p2[0]; r2.y = p2[65536]; r2.z = p2[131072]; r2.w = p2[196608];
    }
  }

#pragma unroll 1
  for (int cc = 0; cc < 16; ++cc) {     // 16 chunks x 4 channels
    __syncthreads();                    // prev phase's reads complete
    *(float4*)(lds + loff0) = make_float4(r0.x*msk0, r0.y*msk0, r0.z*msk0, r0.w*msk0);
    *(float4*)(lds + loff1) = make_float4(r1.x*msk1, r1.y*msk1, r1.z*msk1, r1.w*msk1);
    if (has2)
      *(float4*)(lds + loff2) = make_float4(r2.x*msk2, r2.y*msk2, r2.z*msk2, r2.w*msk2);
    __syncthreads();                    // writes visible

    if (cc < 15) {                      // issue next chunk's loads (no wait)
      const float* base = m_in + (((b * 64 + (cc + 1) * 4) * 4 + t) << 14);
      const float* p0 = base + goff0;
      r0.x = p0[0]; r0.y = p0[65536]; r0.z = p0[131072]; r0.w = p0[196608];
      const float* p1 = base + goff1;
      r1.x = p1[0]; r1.y = p1[65536]; r1.z = p1[131072]; r1.w = p1[196608];
      if (has2) {
        const float* p2 = base + goff2;
        r2.x = p2[0]; r2.y = p2[65536]; r2.z = p2[131072]; r2.w = p2[196608];
      }
    }

    float q0[4];
#pragma unroll
    for (int k = 0; k < 4; ++k)
      q0[k] = q_in[((b * 64 + cc * 4 + k) << 14) + (h << 7) + w];
#pragma unroll
    for (int dy = 0; dy < 7; ++dy)
#pragma unroll
      for (int dx = 0; dx < 7; ++dx) {
        const float4 mv = *(const float4*)&m_s[ty + dy][tx + 1 + dx][0];
        acc[dy * 7 + dx] += q0[0]*mv.x + q0[1]*mv.y + q0[2]*mv.z + q0[3]*mv.w;
      }
  }

  const int obase = ATTN_OFF + ((b * 196 + t) << 14) + (h << 7) + w;
#pragma unroll
  for (int d = 0; d < 49; ++d)
    out[obase + ((d * 4) << 14)] = acc[d];
}

// ---------------------------------------------------------------------------
// K2 (FROZEN, near BW floor): softmax + packed-attn write into d_ws.
// Packed layout keyed to k3's wave tiling: G = (h>>1)*4 + (w>>5),
// lane = (h&1)*32 + (w&31); element (b,G,t,g,lane) at
// ((b*256+G)*4+t)*13*64 + g*64 + lane   (float4 units, d = 4g+j).
// ---------------------------------------------------------------------------
__global__ __launch_bounds__(256) void k2_softmax(
    float* __restrict__ out, const float* __restrict__ cst,
    float4* __restrict__ ws)
{
  const int tid = threadIdx.x;
  const int pl = tid & 63;             // pixel within block
  const int t  = tid >> 6;
  const int pix = blockIdx.x * 64 + pl;      // 65536 pixels total
  const int b = pix >> 14, hw = pix & 16383;
  float* base = out + ATTN_OFF + ((b * 196 + t) << 14) + hw;

  float v[49];
#pragma unroll
  for (int d = 0; d < 49; ++d) v[d] = base[(d * 4) << 14];

  float mx = -1e30f;
#pragma unroll
  for (int d = 0; d < 49; ++d) mx = fmaxf(mx, v[d]);

  __shared__ float red[4][64];
  red[t][pl] = mx;
  __syncthreads();
  float M = fmaxf(fmaxf(red[0][pl], red[1][pl]), fmaxf(red[2][pl], red[3][pl]));
  M = fmaxf(M, cst[0]);
  __syncthreads();

  float s = 0.f;
#pragma unroll
  for (int d = 0; d < 49; ++d) { v[d] = __expf(v[d] - M); s += v[d]; }
  red[t][pl] = s;
  __syncthreads();
  const float l = red[0][pl] + red[1][pl] + red[2][pl] + red[3][pl]
                + __expf(cst[0] - M);
  const float inv = 1.f / l;
#pragma unroll
  for (int d = 0; d < 49; ++d) {
    const float r = v[d] * inv;
    base[(d * 4) << 14] = r;           // reference-layout output (validated)
    v[d] = r;
  }

  if (ws) {
    const int h = hw >> 7, wc = hw & 127;
    const int G    = ((h >> 1) << 2) + (wc >> 5);
    const int lane = ((h & 1) << 5) + (wc & 31);
    float4* dst = ws + (size_t)(((b * 256 + G) * 4 + t) * 13) * 64 + lane;
#pragma unroll
    for (int g = 0; g < 13; ++g) {
      float4 p;
      p.x = v[g * 4];
      p.y = (g < 12) ? v[g * 4 + 1] : 0.f;
      p.z = (g < 12) ? v[g * 4 + 2] : 0.f;
      p.w = (g < 12) ? v[g * 4 + 3] : 0.f;
      dst[g * 64] = p;
    }
  }
}

// ---------------------------------------------------------------------------
// K3 v6 (packed-ws): v5 + cq-fastest XCD swizzle + early-issue staging.
//  - swizzle: l = (p%8)*256 + p/8; cq = l&7, tile = l>>3. Each XCD owns
//    32 tiles x all 8 cq-siblings consecutively -> the 8 blocks reading the
//    SAME 208 KB packed attn share one L2; y-adjacent tiles co-located ->
//    m_out halo L2 hits. (R12: FETCH 173 MB = halo x2 + ws x8 re-reads.)
//  - early-issue (k1-v11 pattern): hoisted item decomposition, 5 named
//    float4 in-flight; next-t m_out loads issued before compute so the
//    vmcnt wait hides under a full compute phase.
//  - mask-multiply zeros + unchanged accumulation order: numerics identical.
// ---------------------------------------------------------------------------
__global__ __launch_bounds__(256) void k3_read_ws(
    const float* __restrict__ m_out, float* __restrict__ out,
    const float4* __restrict__ ws)
{
  // bijective XCD swizzle (2048 % 8 == 0), cq fastest within each XCD
  const int p = blockIdx.x + (blockIdx.y << 2) + (blockIdx.z << 6);
  const int l = ((p & 7) << 8) + (p >> 3);
  const int cq = l & 7;
  const int tile = l >> 3;
  const int bx = tile & 3, by = (tile >> 2) & 15, b = tile >> 6;

  const int h0 = by * 8, w0 = bx * 32;
  const int tid = threadIdx.x;
  const int tx = tid & 31, ty = tid >> 5;
  const int h = h0 + ty, w = w0 + tx;
  const int waveid = tid >> 6, lane = tid & 63;
  const int G = ((h0 >> 1) + waveid) * 4 + bx;

  __shared__ float m_s[2][14][42][4];  // 18,816 B
  float* const lds = &m_s[0][0][0][0];

  float acc[8];
#pragma unroll
  for (int i = 0; i < 8; ++i) acc[i] = 0.f;

  // ---- t-invariant item decomposition (1064 = 2 quads x 14 rows x 38 xi)
  // items k=0..3 always valid (tid+768 <= 1023 < 1064); k=4 iff tid < 40.
  int goff0, goff1, goff2, goff3, goff4;
  int loff0, loff1, loff2, loff3, loff4;
  float msk0, msk1, msk2, msk3, msk4;
#define K3_DECOMP(K, GO, LO, MS)                                           \
  {                                                                        \
    const int it  = (tid + (K << 8)) < 1064 ? (tid + (K << 8)) : 1063;     \
    const int qd  = it >= 532;                                             \
    const int rem = it - 532 * qd;                                         \
    const int yy  = rem / 38;                                              \
    const int xx  = rem - 38 * yy;                                         \
    const int gy  = h0 - 3 + yy, gx = w0 - 3 + xx;                         \
    MS = (((unsigned)gy < 128u) && ((unsigned)gx < 128u)) ? 1.f : 0.f;     \
    const int gyc = gy < 0 ? 0 : (gy > 127 ? 127 : gy);                    \
    const int gxc = gx < 0 ? 0 : (gx > 127 ? 127 : gx);                    \
    GO = (qd << 18) + (gyc << 7) + gxc;                                    \
    LO = (((qd * 14 + yy) * 42) + xx + 1) << 2;                            \
  }
  K3_DECOMP(0, goff0, loff0, msk0)
  K3_DECOMP(1, goff1, loff1, msk1)
  K3_DECOMP(2, goff2, loff2, msk2)
  K3_DECOMP(3, goff3, loff3, msk3)
  K3_DECOMP(4, goff4, loff4, msk4)
#undef K3_DECOMP
  const bool has4 = (tid < 40);

  // ---- prologue: load t=0 into held regs ----
  float4 r0, r1, r2, r3, r4;
#define K3_LOAD(T)                                                         \
  {                                                                        \
    const float* base = m_out + (((b * 64 + cq * 8) * 4 + (T)) << 14);     \
    const float* q;                                                        \
    q = base + goff0; r0.x = q[0]; r0.y = q[65536]; r0.z = q[131072]; r0.w = q[196608]; \
    q = base + goff1; r1.x = q[0]; r1.y = q[65536]; r1.z = q[131072]; r1.w = q[196608]; \
    q = base + goff2; r2.x = q[0]; r2.y = q[65536]; r2.z = q[131072]; r2.w = q[196608]; \
    q = base + goff3; r3.x = q[0]; r3.y = q[65536]; r3.z = q[131072]; r3.w = q[196608]; \
    if (has4) { q = base + goff4;                                          \
      r4.x = q[0]; r4.y = q[65536]; r4.z = q[131072]; r4.w = q[196608]; }  \
  }
  r4 = make_float4(0.f, 0.f, 0.f, 0.f);
  K3_LOAD(0)

#pragma unroll 1
  for (int t = 0; t < 4; ++t) {
    const float4* ap = ws + (size_t)(((b * 256 + G) * 4 + t) * 13) * 64 + lane;

    __syncthreads();                   // prev phase's reads complete
    *(float4*)(lds + loff0) = make_float4(r0.x*msk0, r0.y*msk0, r0.z*msk0, r0.w*msk0);
    *(float4*)(lds + loff1) = make_float4(r1.x*msk1, r1.y*msk1, r1.z*msk1, r1.w*msk1);
    *(float4*)(lds + loff2) = make_float4(r2.x*msk2, r2.y*msk2, r2.z*msk2, r2.w*msk2);
    *(float4*)(lds + loff3) = make_float4(r3.x*msk3, r3.y*msk3, r3.z*msk3, r3.w*msk3);
    if (has4)
      *(float4*)(lds + loff4) = make_float4(r4.x*msk4, r4.y*msk4, r4.z*msk4, r4.w*msk4);
    __syncthreads();                   // writes visible

    if (t < 3) K3_LOAD(t + 1)          // issue next t's loads (no wait)

    float4 cur = ap[0];
#pragma unroll
    for (int g = 0; g < 13; ++g) {
      float4 nxt = cur;
      if (g < 12) nxt = ap[(g + 1) * 64];
#pragma unroll
      for (int j = 0; j < 4; ++j) {
        const int d = g * 4 + j;
        if (d >= 49) break;
        const int dy = d / 7, dx = d % 7;
        const float av = (j == 0) ? cur.x : (j == 1) ? cur.y
                       : (j == 2) ? cur.z : cur.w;
#pragma unroll
        for (int q = 0; q < 2; ++q) {
          const float4 mv = *(const float4*)&m_s[q][ty + dy][tx + dx + 1][0];
          acc[q * 4 + 0] += av * mv.x;
          acc[q * 4 + 1] += av * mv.y;
          acc[q * 4 + 2] += av * mv.z;
          acc[q * 4 + 3] += av * mv.w;
        }
      }
      cur = nxt;
    }
  }
#undef K3_LOAD

#pragma unroll
  for (int q = 0; q < 2; ++q)
#pragma unroll
    for (int k = 0; k < 4; ++k)
      out[((b * 64 + cq * 8 + q * 4 + k) << 14) + (h << 7) + w] = acc[q * 4 + k];
}

// ---------------------------------------------------------------------------
// K3 fallback (unchanged) — used only if ws_size is too small.
// ---------------------------------------------------------------------------
__global__ __launch_bounds__(256) void k3_read_fb(
    const float* __restrict__ m_out, float* __restrict__ out)
{
  const int b = blockIdx.z >> 2, cq = blockIdx.z & 3;
  const int h0 = blockIdx.y * 8, w0 = blockIdx.x * 32;
  const int tid = threadIdx.x;
  const int tx = tid & 31, ty = tid >> 5;
  const int h = h0 + ty, w = w0 + tx;

  __shared__ float m_s[4][14][38][4];
  const float* __restrict__ attn = out + ATTN_OFF;

  float acc[16];
#pragma unroll
  for (int i = 0; i < 16; ++i) acc[i] = 0.f;

#pragma unroll 1
  for (int t = 0; t < 4; ++t) {
    float a[49];
#pragma unroll
    for (int d = 0; d < 49; ++d)
      a[d] = attn[((b * 196 + d * 4 + t) << 14) + (h << 7) + w];

    __syncthreads();
    for (int e = tid; e < 8512; e += 256) {
      int c16 = e / 532; int rem = e - c16 * 532;
      int y = rem / 38;  int x = rem - y * 38;
      int gy = h0 - 3 + y, gx = w0 - 3 + x;
      float v = 0.f;
      if (gy >= 0 && gy < 128 && gx >= 0 && gx < 128)
        v = m_out[(((b * 64 + cq * 16 + c16) * 4 + t) << 14) + (gy << 7) + gx];
      m_s[c16 >> 2][y][x][c16 & 3] = v;
    }
    __syncthreads();

#pragma unroll
    for (int dy = 0; dy < 7; ++dy)
#pragma unroll
      for (int dx = 0; dx < 7; ++dx) {
        const float av = a[dy * 7 + dx];
#pragma unroll
        for (int q = 0; q < 4; ++q) {
          const float4 mv = *(const float4*)&m_s[q][ty + dy][tx + dx][0];
          acc[q * 4 + 0] += av * mv.x;
          acc[q * 4 + 1] += av * mv.y;
          acc[q * 4 + 2] += av * mv.z;
          acc[q * 4 + 3] += av * mv.w;
        }
      }
  }

#pragma unroll
  for (int q = 0; q < 4; ++q)
#pragma unroll
    for (int k = 0; k < 4; ++k)
      out[((b * 64 + cq * 16 + q * 4 + k) << 14) + (h << 7) + w] = acc[q * 4 + k];
}

extern "C" void kernel_launch(void* const* d_in, const int* in_sizes, int n_in,
                              void* d_out, int out_size, void* d_ws, size_t ws_size,
                              hipStream_t stream) {
  const float* m_in  = (const float*)d_in[0];
  const float* m_out = (const float*)d_in[1];
  const float* q_in  = (const float*)d_in[2];
  const float* cst   = (const float*)d_in[3];
  float* out = (float*)d_out;

  const bool use_ws = (ws_size >= WS_F4_COUNT * 16ull) && d_ws != nullptr;
  float4* ws = use_ws ? (float4*)d_ws : nullptr;

  k1_corr<<<dim3(4, 16, 16), dim3(256), 0, stream>>>(m_in, q_in, out);
  k2_softmax<<<dim3(1024), dim3(256), 0, stream>>>(out, cst, ws);
  if (use_ws)
    k3_read_ws<<<dim3(4, 16, 32), dim3(256), 0, stream>>>(m_out, out, ws);
  else
    k3_read_fb<<<dim3(4, 16, 16), dim3(256), 0, stream>>>(m_out, out);
}

// Round 14
// 124.321 us; speedup vs baseline: 1.3308x; 1.0504x over previous
//
#include <hip/hip_runtime.h>

// Problem constants: B=4, De=Do=64, T=4, H=W=128, PATCH=7, R=3
#define ATTN_OFF 4194304                 // B*Do*H*W (mem region size in floats)
// packed attn ws: [b][G=256][t][13][64] float4  = 3,407,872 float4s
#define WS_F4_COUNT 3407872ull

// ---------------------------------------------------------------------------
// K1 v12: 2-vertical-px window sharing on the full validated stack.
//  - R13 model: v11 (1 px/thread) sits AT its LDS-pipe floor (784 b128/thr
//    -> 63 us/CU). 2-px sharing cuts reads/px 1.75x (56/chunk serve 2 px)
//    -> 36 us floor. FMA count unchanged.
//  - tile 32x16, 512 blocks, LDS [22][42][4] = 14,784 B, XCD swizzle
//    (512%8==0), conflict-free b128 staging, early-issue/write-late
//    pipeline + q prefetch (R12-proven latency cover).
//  - __launch_bounds__(256,1): VGPR cap 512 -> no spill at ~160 live
//    (R2/R5 spills were the (256,2)=128-cap; R3 compiled 152 clean).
//  - channel order ascending 4-at-a-time, mask-multiplied zeros ->
//    numerics identical.
// ---------------------------------------------------------------------------
__global__ __launch_bounds__(256, 1) void k1_corr(
    const float* __restrict__ m_in, const float* __restrict__ q_in,
    float* __restrict__ out)
{
  // bijective XCD swizzle (512 % 8 == 0)
  const int p = blockIdx.x + (blockIdx.y << 2) + (blockIdx.z << 5);
  const int l = ((p & 7) << 6) + (p >> 3);
  const int bx = l & 3, by = (l >> 2) & 7, bz = l >> 5;

  const int b = bz >> 2, t = bz & 3;
  const int h0 = by * 16, w0 = bx * 32;
  const int tid = threadIdx.x;
  const int tx = tid & 31, ty = tid >> 5;      // ty 0..7 -> px rows 2ty, 2ty+1

  // [y 0..21][x 0..41][c%4]; slot xi+1 <-> gx = w0-3+xi
  __shared__ float m_s[22][42][4];      // 14,784 B
  float* const lds = &m_s[0][0][0];

  float acc0[49], acc1[49];
#pragma unroll
  for (int d = 0; d < 49; ++d) { acc0[d] = 0.f; acc1[d] = 0.f; }

  // ---- chunk-invariant decomposition (836 items = 22 rows x 38 xi) ----
  // k=0,1,2 always valid (tid+512 <= 767 < 836); k=3 iff tid < 68.
  int goff0, goff1, goff2, goff3, loff0, loff1, loff2, loff3;
  float msk0, msk1, msk2, msk3;
#define K1_DECOMP(K, GO, LO, MS)                                           \
  {                                                                        \
    const int it = (tid + (K << 8)) < 836 ? (tid + (K << 8)) : 835;        \
    const int yy = it / 38;                                                \
    const int xx = it - 38 * yy;                                           \
    const int gy = h0 - 3 + yy, gx = w0 - 3 + xx;                          \
    MS = (((unsigned)gy < 128u) && ((unsigned)gx < 128u)) ? 1.f : 0.f;     \
    const int gyc = gy < 0 ? 0 : (gy > 127 ? 127 : gy);                    \
    const int gxc = gx < 0 ? 0 : (gx > 127 ? 127 : gx);                    \
    GO = (gyc << 7) + gxc;                                                 \
    LO = (yy * 42 + xx + 1) << 2;                                          \
  }
  K1_DECOMP(0, goff0, loff0, msk0)
  K1_DECOMP(1, goff1, loff1, msk1)
  K1_DECOMP(2, goff2, loff2, msk2)
  K1_DECOMP(3, goff3, loff3, msk3)
#undef K1_DECOMP
  const bool has3 = (tid < 68);

  const int qpix = ((h0 + 2 * ty) << 7) + w0 + tx;   // px0; px1 = +128

  // ---- prologue: chunk 0 m_in -> regs, chunk 0 q -> regs ----
  float4 r0, r1, r2, r3;
  float qa[4], qb[4];
#define K1_LOAD(CC)                                                        \
  {                                                                        \
    const float* base = m_in + (((b * 64 + (CC) * 4) * 4 + t) << 14);      \
    const float* q;                                                        \
    q = base + goff0; r0.x = q[0]; r0.y = q[65536]; r0.z = q[131072]; r0.w = q[196608]; \
    q = base + goff1; r1.x = q[0]; r1.y = q[65536]; r1.z = q[131072]; r1.w = q[196608]; \
    q = base + goff2; r2.x = q[0]; r2.y = q[65536]; r2.z = q[131072]; r2.w = q[196608]; \
    if (has3) { q = base + goff3;                                          \
      r3.x = q[0]; r3.y = q[65536]; r3.z = q[131072]; r3.w = q[196608]; }  \
  }
  r3 = make_float4(0.f, 0.f, 0.f, 0.f);
  K1_LOAD(0)
#pragma unroll
  for (int k = 0; k < 4; ++k) {
    const float* qp = q_in + ((b * 64 + k) << 14) + qpix;
    qa[k] = qp[0];
    qb[k] = qp[128];
  }

#pragma unroll 1
  for (int cc = 0; cc < 16; ++cc) {     // 16 chunks x 4 channels
    __syncthreads();                    // prev phase's reads complete
    *(float4*)(lds + loff0) = make_float4(r0.x*msk0, r0.y*msk0, r0.z*msk0, r0.w*msk0);
    *(float4*)(lds + loff1) = make_float4(r1.x*msk1, r1.y*msk1, r1.z*msk1, r1.w*msk1);
    *(float4*)(lds + loff2) = make_float4(r2.x*msk2, r2.y*msk2, r2.z*msk2, r2.w*msk2);
    if (has3)
      *(float4*)(lds + loff3) = make_float4(r3.x*msk3, r3.y*msk3, r3.z*msk3, r3.w*msk3);
    __syncthreads();                    // writes visible

    float qan[4], qbn[4];
    if (cc < 15) {                      // issue next chunk's loads (no wait)
      K1_LOAD(cc + 1)
#pragma unroll
      for (int k = 0; k < 4; ++k) {
        const float* qp = q_in + ((b * 64 + (cc + 1) * 4 + k) << 14) + qpix;
        qan[k] = qp[0];
        qbn[k] = qp[128];
      }
    }

    // compute: shared 8-row window feeds both pixels
#pragma unroll
    for (int wr = 0; wr < 8; ++wr) {
      const float4* rowp = (const float4*)&m_s[2 * ty + wr][tx + 1][0];
#pragma unroll
      for (int dx = 0; dx < 7; ++dx) {
        const float4 mv = rowp[dx];
        if (wr < 7)
          acc0[wr * 7 + dx] += qa[0]*mv.x + qa[1]*mv.y + qa[2]*mv.z + qa[3]*mv.w;
        if (wr > 0)
          acc1[(wr - 1) * 7 + dx] += qb[0]*mv.x + qb[1]*mv.y + qb[2]*mv.z + qb[3]*mv.w;
      }
    }

    if (cc < 15) {
#pragma unroll
      for (int k = 0; k < 4; ++k) { qa[k] = qan[k]; qb[k] = qbn[k]; }
    }
  }
#undef K1_LOAD

  const int obase = ATTN_OFF + ((b * 196 + t) << 14)
                  + ((h0 + 2 * ty) << 7) + w0 + tx;
#pragma unroll
  for (int d = 0; d < 49; ++d) {
    out[obase +       ((d * 4) << 14)] = acc0[d];
    out[obase + 128 + ((d * 4) << 14)] = acc1[d];
  }
}

// ---------------------------------------------------------------------------
// K2 (FROZEN, near BW floor): softmax + packed-attn write into d_ws.
// Packed layout keyed to k3's wave tiling: G = (h>>1)*4 + (w>>5),
// lane = (h&1)*32 + (w&31); element (b,G,t,g,lane) at
// ((b*256+G)*4+t)*13*64 + g*64 + lane   (float4 units, d = 4g+j).
// ---------------------------------------------------------------------------
__global__ __launch_bounds__(256) void k2_softmax(
    float* __restrict__ out, const float* __restrict__ cst,
    float4* __restrict__ ws)
{
  const int tid = threadIdx.x;
  const int pl = tid & 63;             // pixel within block
  const int t  = tid >> 6;
  const int pix = blockIdx.x * 64 + pl;      // 65536 pixels total
  const int b = pix >> 14, hw = pix & 16383;
  float* base = out + ATTN_OFF + ((b * 196 + t) << 14) + hw;

  float v[49];
#pragma unroll
  for (int d = 0; d < 49; ++d) v[d] = base[(d * 4) << 14];

  float mx = -1e30f;
#pragma unroll
  for (int d = 0; d < 49; ++d) mx = fmaxf(mx, v[d]);

  __shared__ float red[4][64];
  red[t][pl] = mx;
  __syncthreads();
  float M = fmaxf(fmaxf(red[0][pl], red[1][pl]), fmaxf(red[2][pl], red[3][pl]));
  M = fmaxf(M, cst[0]);
  __syncthreads();

  float s = 0.f;
#pragma unroll
  for (int d = 0; d < 49; ++d) { v[d] = __expf(v[d] - M); s += v[d]; }
  red[t][pl] = s;
  __syncthreads();
  const float l = red[0][pl] + red[1][pl] + red[2][pl] + red[3][pl]
                + __expf(cst[0] - M);
  const float inv = 1.f / l;
#pragma unroll
  for (int d = 0; d < 49; ++d) {
    const float r = v[d] * inv;
    base[(d * 4) << 14] = r;           // reference-layout output (validated)
    v[d] = r;
  }

  if (ws) {
    const int h = hw >> 7, wc = hw & 127;
    const int G    = ((h >> 1) << 2) + (wc >> 5);
    const int lane = ((h & 1) << 5) + (wc & 31);
    float4* dst = ws + (size_t)(((b * 256 + G) * 4 + t) * 13) * 64 + lane;
#pragma unroll
    for (int g = 0; g < 13; ++g) {
      float4 p;
      p.x = v[g * 4];
      p.y = (g < 12) ? v[g * 4 + 1] : 0.f;
      p.z = (g < 12) ? v[g * 4 + 2] : 0.f;
      p.w = (g < 12) ? v[g * 4 + 3] : 0.f;
      dst[g * 64] = p;
    }
  }
}

// ---------------------------------------------------------------------------
// K3 v6 (FROZEN, wall-validated R13): cq-fastest XCD swizzle + early-issue
// staging, 8-channel blocks, conflict-free staging, g-pipelined ws reads.
// ---------------------------------------------------------------------------
__global__ __launch_bounds__(256) void k3_read_ws(
    const float* __restrict__ m_out, float* __restrict__ out,
    const float4* __restrict__ ws)
{
  // bijective XCD swizzle (2048 % 8 == 0), cq fastest within each XCD
  const int p = blockIdx.x + (blockIdx.y << 2) + (blockIdx.z << 6);
  const int l = ((p & 7) << 8) + (p >> 3);
  const int cq = l & 7;
  const int tile = l >> 3;
  const int bx = tile & 3, by = (tile >> 2) & 15, b = tile >> 6;

  const int h0 = by * 8, w0 = bx * 32;
  const int tid = threadIdx.x;
  const int tx = tid & 31, ty = tid >> 5;
  const int h = h0 + ty, w = w0 + tx;
  const int waveid = tid >> 6, lane = tid & 63;
  const int G = ((h0 >> 1) + waveid) * 4 + bx;

  __shared__ float m_s[2][14][42][4];  // 18,816 B
  float* const lds = &m_s[0][0][0][0];

  float acc[8];
#pragma unroll
  for (int i = 0; i < 8; ++i) acc[i] = 0.f;

  int goff0, goff1, goff2, goff3, goff4;
  int loff0, loff1, loff2, loff3, loff4;
  float msk0, msk1, msk2, msk3, msk4;
#define K3_DECOMP(K, GO, LO, MS)                                           \
  {                                                                        \
    const int it  = (tid + (K << 8)) < 1064 ? (tid + (K << 8)) : 1063;     \
    const int qd  = it >= 532;                                             \
    const int rem = it - 532 * qd;                                         \
    const int yy  = rem / 38;                                              \
    const int xx  = rem - 38 * yy;                                         \
    const int gy  = h0 - 3 + yy, gx = w0 - 3 + xx;                         \
    MS = (((unsigned)gy < 128u) && ((unsigned)gx < 128u)) ? 1.f : 0.f;     \
    const int gyc = gy < 0 ? 0 : (gy > 127 ? 127 : gy);                    \
    const int gxc = gx < 0 ? 0 : (gx > 127 ? 127 : gx);                    \
    GO = (qd << 18) + (gyc << 7) + gxc;                                    \
    LO = (((qd * 14 + yy) * 42) + xx + 1) << 2;                            \
  }
  K3_DECOMP(0, goff0, loff0, msk0)
  K3_DECOMP(1, goff1, loff1, msk1)
  K3_DECOMP(2, goff2, loff2, msk2)
  K3_DECOMP(3, goff3, loff3, msk3)
  K3_DECOMP(4, goff4, loff4, msk4)
#undef K3_DECOMP
  const bool has4 = (tid < 40);

  float4 r0, r1, r2, r3, r4;
#define K3_LOAD(T)                                                         \
  {                                                                        \
    const float* base = m_out + (((b * 64 + cq * 8) * 4 + (T)) << 14);     \
    const float* q;                                                        \
    q = base + goff0; r0.x = q[0]; r0.y = q[65536]; r0.z = q[131072]; r0.w = q[196608]; \
    q = base + goff1; r1.x = q[0]; r1.y = q[65536]; r1.z = q[131072]; r1.w = q[196608]; \
    q = base + goff2; r2.x = q[0]; r2.y = q[65536]; r2.z = q[131072]; r2.w = q[196608]; \
    q = base + goff3; r3.x = q[0]; r3.y = q[65536]; r3.z = q[131072]; r3.w = q[196608]; \
    if (has4) { q = base + goff4;                                          \
      r4.x = q[0]; r4.y = q[65536]; r4.z = q[131072]; r4.w = q[196608]; }  \
  }
  r4 = make_float4(0.f, 0.f, 0.f, 0.f);
  K3_LOAD(0)

#pragma unroll 1
  for (int t = 0; t < 4; ++t) {
    const float4* ap = ws + (size_t)(((b * 256 + G) * 4 + t) * 13) * 64 + lane;

    __syncthreads();                   // prev phase's reads complete
    *(float4*)(lds + loff0) = make_float4(r0.x*msk0, r0.y*msk0, r0.z*msk0, r0.w*msk0);
    *(float4*)(lds + loff1) = make_float4(r1.x*msk1, r1.y*msk1, r1.z*msk1, r1.w*msk1);
    *(float4*)(lds + loff2) = make_float4(r2.x*msk2, r2.y*msk2, r2.z*msk2, r2.w*msk2);
    *(float4*)(lds + loff3) = make_float4(r3.x*msk3, r3.y*msk3, r3.z*msk3, r3.w*msk3);
    if (has4)
      *(float4*)(lds + loff4) = make_float4(r4.x*msk4, r4.y*msk4, r4.z*msk4, r4.w*msk4);
    __syncthreads();                   // writes visible

    if (t < 3) K3_LOAD(t + 1)          // issue next t's loads (no wait)

    float4 cur = ap[0];
#pragma unroll
    for (int g = 0; g < 13; ++g) {
      float4 nxt = cur;
      if (g < 12) nxt = ap[(g + 1) * 64];
#pragma unroll
      for (int j = 0; j < 4; ++j) {
        const int d = g * 4 + j;
        if (d >= 49) break;
        const int dy = d / 7, dx = d % 7;
        const float av = (j == 0) ? cur.x : (j == 1) ? cur.y
                       : (j == 2) ? cur.z : cur.w;
#pragma unroll
        for (int q = 0; q < 2; ++q) {
          const float4 mv = *(const float4*)&m_s[q][ty + dy][tx + dx + 1][0];
          acc[q * 4 + 0] += av * mv.x;
          acc[q * 4 + 1] += av * mv.y;
          acc[q * 4 + 2] += av * mv.z;
          acc[q * 4 + 3] += av * mv.w;
        }
      }
      cur = nxt;
    }
  }
#undef K3_LOAD

#pragma unroll
  for (int q = 0; q < 2; ++q)
#pragma unroll
    for (int k = 0; k < 4; ++k)
      out[((b * 64 + cq * 8 + q * 4 + k) << 14) + (h << 7) + w] = acc[q * 4 + k];
}

// ---------------------------------------------------------------------------
// K3 fallback (unchanged) — used only if ws_size is too small.
// ---------------------------------------------------------------------------
__global__ __launch_bounds__(256) void k3_read_fb(
    const float* __restrict__ m_out, float* __restrict__ out)
{
  const int b = blockIdx.z >> 2, cq = blockIdx.z & 3;
  const int h0 = blockIdx.y * 8, w0 = blockIdx.x * 32;
  const int tid = threadIdx.x;
  const int tx = tid & 31, ty = tid >> 5;
  const int h = h0 + ty, w = w0 + tx;

  __shared__ float m_s[4][14][38][4];
  const float* __restrict__ attn = out + ATTN_OFF;

  float acc[16];
#pragma unroll
  for (int i = 0; i < 16; ++i) acc[i] = 0.f;

#pragma unroll 1
  for (int t = 0; t < 4; ++t) {
    float a[49];
#pragma unroll
    for (int d = 0; d < 49; ++d)
      a[d] = attn[((b * 196 + d * 4 + t) << 14) + (h << 7) + w];

    __syncthreads();
    for (int e = tid; e < 8512; e += 256) {
      int c16 = e / 532; int rem = e - c16 * 532;
      int y = rem / 38;  int x = rem - y * 38;
      int gy = h0 - 3 + y, gx = w0 - 3 + x;
      float v = 0.f;
      if (gy >= 0 && gy < 128 && gx >= 0 && gx < 128)
        v = m_out[(((b * 64 + cq * 16 + c16) * 4 + t) << 14) + (gy << 7) + gx];
      m_s[c16 >> 2][y][x][c16 & 3] = v;
    }
    __syncthreads();

#pragma unroll
    for (int dy = 0; dy < 7; ++dy)
#pragma unroll
      for (int dx = 0; dx < 7; ++dx) {
        const float av = a[dy * 7 + dx];
#pragma unroll
        for (int q = 0; q < 4; ++q) {
          const float4 mv = *(const float4*)&m_s[q][ty + dy][tx + dx][0];
          acc[q * 4 + 0] += av * mv.x;
          acc[q * 4 + 1] += av * mv.y;
          acc[q * 4 + 2] += av * mv.z;
          acc[q * 4 + 3] += av * mv.w;
        }
      }
  }

#pragma unroll
  for (int q = 0; q < 4; ++q)
#pragma unroll
    for (int k = 0; k < 4; ++k)
      out[((b * 64 + cq * 16 + q * 4 + k) << 14) + (h << 7) + w] = acc[q * 4 + k];
}

extern "C" void kernel_launch(void* const* d_in, const int* in_sizes, int n_in,
                              void* d_out, int out_size, void* d_ws, size_t ws_size,
                              hipStream_t stream) {
  const float* m_in  = (const float*)d_in[0];
  const float* m_out = (const float*)d_in[1];
  const float* q_in  = (const float*)d_in[2];
  const float* cst   = (const float*)d_in[3];
  float* out = (float*)d_out;

  const bool use_ws = (ws_size >= WS_F4_COUNT * 16ull) && d_ws != nullptr;
  float4* ws = use_ws ? (float4*)d_ws : nullptr;

  k1_corr<<<dim3(4, 8, 16), dim3(256), 0, stream>>>(m_in, q_in, out);
  k2_softmax<<<dim3(1024), dim3(256), 0, stream>>>(out, cst, ws);
  if (use_ws)
    k3_read_ws<<<dim3(4, 16, 32), dim3(256), 0, stream>>>(m_out, out, ws);
  else
    k3_read_fb<<<dim3(4, 16, 16), dim3(256), 0, stream>>>(m_out, out);
}